// Round 1
// baseline (701.089 us; speedup 1.0000x reference)
//
#include <hip/hip_runtime.h>
#include <math.h>

#define NGRAPH 128
#define NPER   512
#define EPER   8192
#define NFEAT  4
#define NREL   5
#define DD     128
#define MAXNB  50
#define MAXW   21
#define NCLS   5
#define NT     1024

// ~132 KB static LDS union: phase A (RGCN) vs phase B/C/D (walk + head).
union SMem {
  struct {                       // RGCN phases
    float u0[NPER * 32];         // basis-0 weighted in-aggregation (fin-space)
    float u1[NPER * 32];         // basis-1
    int   cntD[NPER];            // in-degree
    int   offsD[NPER];           // in-CSR offsets
    float compL[16];             // comp[5][2] staged
  } a;
  struct {                       // walk phases
    int   bucket[EPER];          // out-edge sort buffer, key=(d<<13)|e
    int   cntO[NPER];            // out-degree
    int   offs[NPER];
    int   fill[NPER];
    int   sA[NPER];
    int   sB[NPER];
    int   trav[NPER];
    float wT[DD * 64];           // walk_w transposed [k][j], padded 50->64
    float wb[64];
    float accS[DD];
    float logitsS[64];
    float partL[16 * 64];        // partial dot sums
    float hidS[DD];
    float pooledS[DD];
    int   scal[16];              // 0:node 1:done 2:upd 3:tgt 4:startI 5:endI 6:travcnt
  } b;
};

__device__ __forceinline__ void excl_scan_512(const int* cnt, int* offs,
                                              int* tA, int* tB, int tid) {
  for (int i = tid; i < NPER; i += NT) tA[i] = cnt[i];
  __syncthreads();
  int* a = tA; int* b = tB;
  for (int d = 1; d < NPER; d <<= 1) {
    for (int i = tid; i < NPER; i += NT) {
      int v = a[i];
      if (i >= d) v += a[i - d];
      b[i] = v;
    }
    __syncthreads();
    int* t = a; a = b; b = t;
  }
  for (int i = tid; i < NPER; i += NT) offs[i] = a[i] - cnt[i];  // exclusive
  __syncthreads();
}

__device__ __forceinline__ void sort_bucket(int* bucket, int base, int c) {
  for (int i = 1; i < c; ++i) {          // stable via full key (d<<13)|e
    int key = bucket[base + i];
    int j = i - 1;
    while (j >= 0 && bucket[base + j] > key) {
      bucket[base + j + 1] = bucket[base + j];
      --j;
    }
    bucket[base + j + 1] = key;
  }
}

__global__ __launch_bounds__(NT, 1)
void igmc_kernel(const float* __restrict__ x,
                 const int* __restrict__ esrc, const int* __restrict__ edst,
                 const int* __restrict__ etype,
                 const float* __restrict__ bas0, const float* __restrict__ cmp0,
                 const float* __restrict__ rt0,  const float* __restrict__ bi0,
                 const float* __restrict__ bas1, const float* __restrict__ cmp1,
                 const float* __restrict__ rt1,  const float* __restrict__ bi1,
                 const float* __restrict__ bas2, const float* __restrict__ cmp2,
                 const float* __restrict__ rt2,  const float* __restrict__ bi2,
                 const float* __restrict__ bas3, const float* __restrict__ cmp3,
                 const float* __restrict__ rt3,  const float* __restrict__ bi3,
                 const float* __restrict__ walk_w, const float* __restrict__ walk_b,
                 const float* __restrict__ lin1_w, const float* __restrict__ lin1_b,
                 const float* __restrict__ lin2_w, const float* __restrict__ lin2_b,
                 float* __restrict__ cs, int* __restrict__ gB,
                 float* __restrict__ out) {
  __shared__ SMem sm;
  const int g = blockIdx.x;
  const int tid = threadIdx.x;
  const int nbase = g * NPER;
  const int ebase = g * EPER;

  const float* basA[4] = {bas0, bas1, bas2, bas3};
  const float* cmpA[4] = {cmp0, cmp1, cmp2, cmp3};
  const float* rtA[4]  = {rt0, rt1, rt2, rt3};
  const float* biA[4]  = {bi0, bi1, bi2, bi3};

  // ---------------- Build in-edge CSR (sorted by (dst, edge-id)) ----------------
  {
    int* tb_bucket = (int*)sm.a.u0;        // scratch in u0 region (free now)
    int* tb_fill   = tb_bucket + EPER;
    int* tb_sA     = tb_fill + NPER;
    int* tb_sB     = tb_sA + NPER;
    for (int i = tid; i < NPER; i += NT) { sm.a.cntD[i] = 0; tb_fill[i] = 0; }
    __syncthreads();
    for (int e = tid; e < EPER; e += NT) {
      int d = edst[ebase + e] - nbase;
      atomicAdd(&sm.a.cntD[d], 1);
    }
    __syncthreads();
    excl_scan_512(sm.a.cntD, sm.a.offsD, tb_sA, tb_sB, tid);
    for (int e = tid; e < EPER; e += NT) {
      int d = edst[ebase + e] - nbase;
      int pos = sm.a.offsD[d] + atomicAdd(&tb_fill[d], 1);
      tb_bucket[pos] = (d << 13) | e;
    }
    __syncthreads();
    if (tid < NPER) sort_bucket(tb_bucket, sm.a.offsD[tid], sm.a.cntD[tid]);
    __syncthreads();
    for (int i = tid; i < EPER; i += NT) {
      int e = tb_bucket[i] & (EPER - 1);
      int s = esrc[ebase + e] - nbase;
      int r = etype[ebase + e];
      gB[(size_t)g * EPER + i] = (s << 3) | r;   // packed (src_local, rel)
    }
    __threadfence_block();
    __syncthreads();
  }

  // ---------------- 4 RGCN layers ----------------
  for (int l = 0; l < 4; ++l) {
    const int fin = (l == 0) ? NFEAT : 32;
    const int kb  = (l == 0) ? 2 : 5;
    if (tid < NREL * 2) sm.a.compL[tid] = cmpA[l][tid];
    __syncthreads();

    // gather pass: u_b[n][k] = sum over in-edges of comp[r][b]*h[src][k]
    const int items = NPER << kb;
    for (int it = tid; it < items; it += NT) {
      const int n = it >> kb;
      const int k = it & (fin - 1);
      const int c  = sm.a.cntD[n];
      const int ob = (int)((size_t)g * EPER) + sm.a.offsD[n];
      float s0 = 0.f, s1 = 0.f;
      for (int i = 0; i < c; ++i) {
        const int pe = gB[ob + i];
        const int s = pe >> 3;
        const int r = pe & 7;
        const float hv = (l == 0)
            ? x[(nbase + s) * NFEAT + k]
            : cs[(size_t)(nbase + s) * DD + (l - 1) * 32 + k];
        s0 += sm.a.compL[r * 2 + 0] * hv;
        s1 += sm.a.compL[r * 2 + 1] * hv;
      }
      sm.a.u0[n * fin + k] = s0;
      sm.a.u1[n * fin + k] = s1;
    }
    __syncthreads();

    // node pass: h_new = tanh(u@basis / deg + h@root + bias)
    const float* bas = basA[l];
    const float* rt  = rtA[l];
    const float* bi  = biA[l];
    for (int it = tid; it < NPER * 32; it += NT) {
      const int n = it >> 5;
      const int o = it & 31;
      float agg = 0.f;
      for (int k = 0; k < fin; ++k) {
        agg += sm.a.u0[n * fin + k] * bas[k * 32 + o]
             + sm.a.u1[n * fin + k] * bas[(fin + k) * 32 + o];
      }
      const int dgi = sm.a.cntD[n];
      const float dg = (float)(dgi > 1 ? dgi : 1);
      const float* hrow = (l == 0) ? (x + (size_t)(nbase + n) * NFEAT)
                                   : (cs + (size_t)(nbase + n) * DD + (l - 1) * 32);
      float rv = 0.f;
      for (int k = 0; k < fin; ++k) rv += hrow[k] * rt[k * 32 + o];
      const float v = agg / dg + rv + bi[o];
      cs[(size_t)(nbase + n) * DD + l * 32 + o] = tanhf(v);
    }
    __threadfence_block();
    __syncthreads();
  }

  // ---------------- Out-neighbor table (sorted by (src, dst, edge-id)) ----------------
  for (int i = tid; i < NPER; i += NT) {
    sm.b.cntO[i] = 0; sm.b.fill[i] = 0; sm.b.trav[i] = 0;
  }
  if (tid == 0) { sm.b.scal[6] = 0; sm.b.scal[4] = NPER; sm.b.scal[5] = NPER; }
  __syncthreads();
  for (int e = tid; e < EPER; e += NT) {
    int s = esrc[ebase + e] - nbase;
    atomicAdd(&sm.b.cntO[s], 1);
  }
  if (tid < NPER) {  // start/end detection (argmax of one-hot cols 0/1)
    if (x[(size_t)(nbase + tid) * NFEAT + 0] > 0.5f) atomicMin(&sm.b.scal[4], tid);
    if (x[(size_t)(nbase + tid) * NFEAT + 1] > 0.5f) atomicMin(&sm.b.scal[5], tid);
  }
  __syncthreads();
  excl_scan_512(sm.b.cntO, sm.b.offs, sm.b.sA, sm.b.sB, tid);
  for (int e = tid; e < EPER; e += NT) {
    int s = esrc[ebase + e] - nbase;
    int d = edst[ebase + e] - nbase;
    int pos = sm.b.offs[s] + atomicAdd(&sm.b.fill[s], 1);
    sm.b.bucket[pos] = (d << 13) | e;
  }
  __syncthreads();
  // stage walk_w transposed (pad cols 50..63 with 0) + walk_b
  for (int i = tid; i < DD * 64; i += NT) {
    int k = i >> 6, j = i & 63;
    sm.b.wT[i] = (j < MAXNB) ? walk_w[j * DD + k] : 0.f;
  }
  if (tid < 64) sm.b.wb[tid] = (tid < MAXNB) ? walk_b[tid] : 0.f;
  if (tid < NPER) sort_bucket(sm.b.bucket, sm.b.offs[tid], sm.b.cntO[tid]);
  __syncthreads();

  // ---------------- Walk init ----------------
  int startN = sm.b.scal[4]; if (startN >= NPER) startN = 0;
  int endN   = sm.b.scal[5]; if (endN   >= NPER) endN   = 0;
  if (tid == 0) { sm.b.scal[0] = startN; sm.b.scal[1] = 0; sm.b.trav[startN] = 1; }
  for (int i = tid; i < DD; i += NT)
    sm.b.accS[i] = cs[(size_t)(nbase + startN) * DD + i];
  __syncthreads();

  // ---------------- 21 walk steps (exact jnp.argmax semantics) ----------------
  for (int step = 0; step < MAXW; ++step) {
    {  // partial dots: logits[j] = walk_w[j] . acc + walk_b[j]
      const int j = tid & 63;
      const int part = tid >> 6;             // 16 parts x 8 elements
      const int k0 = part * 8;
      float s = 0.f;
      #pragma unroll
      for (int k = 0; k < 8; ++k) s += sm.b.wT[(k0 + k) * 64 + j] * sm.b.accS[k0 + k];
      sm.b.partL[part * 64 + j] = s;
    }
    __syncthreads();
    if (tid < 64) {  // wave 0: finalize logits, validity, argmax reduce, state update
      const int j = tid;
      float lg = 0.f;
      #pragma unroll
      for (int p = 0; p < 16; ++p) lg += sm.b.partL[p * 64 + j];
      lg += sm.b.wb[j];
      const int node  = sm.b.scal[0];
      const int cnt_n = sm.b.cntO[node];
      const int off_n = sm.b.offs[node];
      const int jmax  = (cnt_n < MAXNB) ? cnt_n : MAXNB;
      float myval = -INFINITY;
      if (j < jmax) {
        int nbj = sm.b.bucket[off_n + j] >> 13;
        if (!sm.b.trav[nbj]) myval = lg;
      }
      int myidx = j;
      #pragma unroll
      for (int o = 1; o < 64; o <<= 1) {
        float ov = __shfl_xor(myval, o, 64);
        int   oi = __shfl_xor(myidx, o, 64);
        if (ov > myval || (ov == myval && oi < myidx)) { myval = ov; myidx = oi; }
      }
      if (j == 0) {
        const int done = sm.b.scal[1];
        const int no_nbr = (cnt_n == 0);
        int sel = no_nbr ? (NPER - 1) : (sm.b.bucket[off_n + myidx] >> 13);
        const int upd  = !done;
        const int move = upd && !no_nbr;
        sm.b.scal[2] = upd;
        sm.b.scal[3] = no_nbr ? endN : sel;
        if (move) sm.b.trav[sel] = 1;
        if (upd && (no_nbr || sel == endN)) sm.b.scal[1] = 1;
        if (move) sm.b.scal[0] = sel;
      }
    }
    __syncthreads();
    if (sm.b.scal[2]) {
      const int tgt = sm.b.scal[3];
      for (int i = tid; i < DD; i += NT)
        sm.b.accS[i] += cs[(size_t)(nbase + tgt) * DD + i];
    }
    __syncthreads();
  }

  // ---------------- Pool + MLP head + log_softmax ----------------
  if (tid < NPER && sm.b.trav[tid]) atomicAdd(&sm.b.scal[6], 1);
  __syncthreads();
  {
    const float tc = (float)sm.b.scal[6];
    for (int i = tid; i < DD; i += NT) sm.b.pooledS[i] = sm.b.accS[i] / tc;
  }
  __syncthreads();
  if (tid < DD) {
    const float4* w4 = (const float4*)(lin1_w + (size_t)tid * DD);
    float s = lin1_b[tid];
    #pragma unroll 8
    for (int k4 = 0; k4 < DD / 4; ++k4) {
      float4 wv = w4[k4];
      s += wv.x * sm.b.pooledS[k4 * 4 + 0] + wv.y * sm.b.pooledS[k4 * 4 + 1]
         + wv.z * sm.b.pooledS[k4 * 4 + 2] + wv.w * sm.b.pooledS[k4 * 4 + 3];
    }
    sm.b.hidS[tid] = fmaxf(s, 0.f);
  }
  __syncthreads();
  if (tid < NCLS) {
    const float4* w4 = (const float4*)(lin2_w + (size_t)tid * DD);
    float s = lin2_b[tid];
    #pragma unroll 8
    for (int k4 = 0; k4 < DD / 4; ++k4) {
      float4 wv = w4[k4];
      s += wv.x * sm.b.hidS[k4 * 4 + 0] + wv.y * sm.b.hidS[k4 * 4 + 1]
         + wv.z * sm.b.hidS[k4 * 4 + 2] + wv.w * sm.b.hidS[k4 * 4 + 3];
    }
    sm.b.logitsS[tid] = s;
  }
  __syncthreads();
  if (tid < NCLS) {
    float m = sm.b.logitsS[0];
    for (int c = 1; c < NCLS; ++c) m = fmaxf(m, sm.b.logitsS[c]);
    float sum = 0.f;
    for (int c = 0; c < NCLS; ++c) sum += expf(sm.b.logitsS[c] - m);
    const float lse = m + logf(sum);
    out[g * NCLS + tid] = sm.b.logitsS[tid] - lse;
  }
}

extern "C" void kernel_launch(void* const* d_in, const int* in_sizes, int n_in,
                              void* d_out, int out_size, void* d_ws, size_t ws_size,
                              hipStream_t stream) {
  const float* x = (const float*)d_in[0];
  const int* ei  = (const int*)d_in[1];
  const int E = in_sizes[1] / 2;
  const int* esrc = ei;
  const int* edst = ei + E;
  const int* et   = (const int*)d_in[2];
  float* cs = (float*)d_ws;                                    // [N, 128] f32 = 32 MB
  int* gB = (int*)((char*)d_ws + (size_t)NGRAPH * NPER * DD * sizeof(float));  // 4 MB
  igmc_kernel<<<dim3(NGRAPH), dim3(NT), 0, stream>>>(
      x, esrc, edst, et,
      (const float*)d_in[4],  (const float*)d_in[5],  (const float*)d_in[6],  (const float*)d_in[7],
      (const float*)d_in[8],  (const float*)d_in[9],  (const float*)d_in[10], (const float*)d_in[11],
      (const float*)d_in[12], (const float*)d_in[13], (const float*)d_in[14], (const float*)d_in[15],
      (const float*)d_in[16], (const float*)d_in[17], (const float*)d_in[18], (const float*)d_in[19],
      (const float*)d_in[20], (const float*)d_in[21],
      (const float*)d_in[22], (const float*)d_in[23],
      (const float*)d_in[24], (const float*)d_in[25],
      cs, gB, (float*)d_out);
}

// Round 2
// 272.946 us; speedup vs baseline: 2.5686x; 2.5686x over previous
//
#include <hip/hip_runtime.h>
#include <math.h>

#define NGRAPH 128
#define NPER   512
#define EPER   8192
#define NFEAT  4
#define NREL   5
#define DD     128
#define MAXNB  50
#define MAXW   21
#define NCLS   5

typedef unsigned short ushortT;

// ===================== Kernel A: build sorted in/out CSRs =====================
// in-CSR: per dst, edges sorted by (dst, e)  -> gBin[pos] = (src_local<<3)|rel
// out-CSR: per src, edges sorted by (dst, e) -> gOut[pos] = dst_local
// packed meta: (offs<<14)|cnt  per node. Also start/end node per graph.
#define NTA 512

__device__ __forceinline__ void scan512(int* cnt, int* offs, int* a, int* b, int tid) {
  a[tid] = cnt[tid];
  __syncthreads();
  int* pa = a; int* pb = b;
  #pragma unroll
  for (int d = 1; d < NPER; d <<= 1) {
    int v = pa[tid];
    if (tid >= d) v += pa[tid - d];
    pb[tid] = v;
    __syncthreads();
    int* t = pa; pa = pb; pb = t;
  }
  offs[tid] = pa[tid] - cnt[tid];
  __syncthreads();
}

__global__ __launch_bounds__(NTA, 1)
void build_csr(const int* __restrict__ esrc, const int* __restrict__ edst,
               const int* __restrict__ etype, const float* __restrict__ x,
               ushortT* __restrict__ gBin, ushortT* __restrict__ gOut,
               int* __restrict__ pIn, int* __restrict__ pOut, int* __restrict__ gSE) {
  __shared__ int bucket[EPER];
  __shared__ int sorted[EPER];
  __shared__ ushortT nodeS[EPER];
  __shared__ int cnt[NPER], offs[NPER], fill[NPER], sA[NPER], sB[NPER];
  __shared__ int se[2];
  const int g = blockIdx.x, tid = threadIdx.x;
  const int nbase = g * NPER, ebase = g * EPER;

  if (tid < 2) se[tid] = NPER;
  cnt[tid] = 0; fill[tid] = 0;
  __syncthreads();
  // start/end detection (first index with one-hot col 0 / col 1 set)
  if (x[(size_t)(nbase + tid) * NFEAT + 0] > 0.5f) atomicMin(&se[0], tid);
  if (x[(size_t)(nbase + tid) * NFEAT + 1] > 0.5f) atomicMin(&se[1], tid);

  // ---- IN CSR (bucket by dst) ----
  for (int e = tid; e < EPER; e += NTA) atomicAdd(&cnt[edst[ebase + e] - nbase], 1);
  __syncthreads();
  scan512(cnt, offs, sA, sB, tid);
  for (int e = tid; e < EPER; e += NTA) {
    int d = edst[ebase + e] - nbase;
    int pos = offs[d] + atomicAdd(&fill[d], 1);
    bucket[pos] = (d << 13) | e;
  }
  __syncthreads();
  // parallel rank-sort within each node slice (keys unique)
  for (int p = tid; p < EPER; p += NTA) {
    const int k = bucket[p];
    const int n = k >> 13;
    const int o = offs[n], c = cnt[n];
    int r = 0;
    for (int i = 0; i < c; ++i) r += (bucket[o + i] < k);
    sorted[o + r] = k;
  }
  __syncthreads();
  for (int p = tid; p < EPER; p += NTA) {
    const int e = sorted[p] & (EPER - 1);
    const int s = esrc[ebase + e] - nbase;
    const int rr = etype[ebase + e];
    gBin[(size_t)g * EPER + p] = (ushortT)((s << 3) | rr);
  }
  pIn[nbase + tid] = (offs[tid] << 14) | cnt[tid];
  if (tid < 2) gSE[g * 2 + tid] = (se[tid] >= NPER) ? 0 : se[tid];
  __syncthreads();

  // ---- OUT CSR (bucket by src, key (dst,e)) ----
  cnt[tid] = 0; fill[tid] = 0;
  __syncthreads();
  for (int e = tid; e < EPER; e += NTA) atomicAdd(&cnt[esrc[ebase + e] - nbase], 1);
  __syncthreads();
  scan512(cnt, offs, sA, sB, tid);
  for (int e = tid; e < EPER; e += NTA) {
    int s = esrc[ebase + e] - nbase;
    int d = edst[ebase + e] - nbase;
    int pos = offs[s] + atomicAdd(&fill[s], 1);
    bucket[pos] = (d << 13) | e;
    nodeS[pos] = (ushortT)s;
  }
  __syncthreads();
  for (int p = tid; p < EPER; p += NTA) {
    const int k = bucket[p];
    const int n = (int)nodeS[p];
    const int o = offs[n], c = cnt[n];
    int r = 0;
    for (int i = 0; i < c; ++i) r += (bucket[o + i] < k);
    sorted[o + r] = k;
  }
  __syncthreads();
  for (int p = tid; p < EPER; p += NTA)
    gOut[(size_t)g * EPER + p] = (ushortT)(sorted[p] >> 13);
  pOut[nbase + tid] = (offs[tid] << 14) | cnt[tid];
}

// ===================== Kernel B: one RGCN layer =====================
template <int FIN>
__global__ __launch_bounds__(256)
void rgcn_layer(const float* __restrict__ x, float* __restrict__ cs,
                const ushortT* __restrict__ gBin, const int* __restrict__ pIn,
                const float* __restrict__ bas, const float* __restrict__ cmp,
                const float* __restrict__ rt, const float* __restrict__ bi, int l) {
  constexpr int LPN = FIN / 4;          // lanes per node
  constexpr int NPB = 256 / LPN;        // nodes per block
  constexpr int BPG = NPER / NPB;       // blocks per graph
  __shared__ float compL[NREL * 2];
  __shared__ float basS[2 * FIN * 32];
  __shared__ float rtS[FIN * 32];
  __shared__ float biS[32];
  __shared__ float u0S[NPB * FIN], u1S[NPB * FIN];
  __shared__ float hT[NPB * FIN];
  __shared__ int cntS[NPB];
  const int bid = blockIdx.x, tid = threadIdx.x;
  const int g = bid / BPG, n0 = (bid % BPG) * NPB;
  const int nbase = g * NPER;

  for (int i = tid; i < NREL * 2; i += 256) compL[i] = cmp[i];
  for (int i = tid; i < 2 * FIN * 32; i += 256) basS[i] = bas[i];
  for (int i = tid; i < FIN * 32; i += 256) rtS[i] = rt[i];
  if (tid < 32) biS[tid] = bi[tid];
  for (int i = tid; i < NPB * FIN; i += 256) {
    const int n = i / FIN, k = i % FIN;
    hT[i] = (FIN == 4) ? x[(size_t)(nbase + n0 + n) * NFEAT + k]
                       : cs[(size_t)(nbase + n0 + n) * DD + (l - 1) * 32 + k];
  }
  __syncthreads();

  // gather: u_b[n][k] = sum over in-edges (e ascending) of comp[r][b]*h[src][k]
  {
    const int group = tid / LPN, q = tid % LPN;
    const int n = n0 + group;
    const int pk = pIn[nbase + n];
    const int off = pk >> 14, c = pk & 16383;
    if (q == 0) cntS[group] = c;
    const ushortT* el = gBin + (size_t)g * EPER + off;
    const float* hbase = (FIN == 4) ? (x + (size_t)nbase * NFEAT)
                                    : (cs + (size_t)nbase * DD + (l - 1) * 32);
    const int stride = (FIN == 4) ? NFEAT : DD;
    float4 s0 = make_float4(0.f, 0.f, 0.f, 0.f);
    float4 s1 = make_float4(0.f, 0.f, 0.f, 0.f);
    for (int i = 0; i < c; ++i) {
      const int pe = (int)el[i];
      const int s = pe >> 3, r = pe & 7;
      const float4 hv = *(const float4*)(hbase + (size_t)s * stride + q * 4);
      const float c0 = compL[r * 2 + 0], c1 = compL[r * 2 + 1];
      s0.x += c0 * hv.x; s0.y += c0 * hv.y; s0.z += c0 * hv.z; s0.w += c0 * hv.w;
      s1.x += c1 * hv.x; s1.y += c1 * hv.y; s1.z += c1 * hv.z; s1.w += c1 * hv.w;
    }
    const int ub = group * FIN + q * 4;
    u0S[ub + 0] = s0.x; u0S[ub + 1] = s0.y; u0S[ub + 2] = s0.z; u0S[ub + 3] = s0.w;
    u1S[ub + 0] = s1.x; u1S[ub + 1] = s1.y; u1S[ub + 2] = s1.z; u1S[ub + 3] = s1.w;
  }
  __syncthreads();

  // node pass: h_new = tanh(u@basis/deg + h@root + bias)
  for (int it = tid; it < NPB * 32; it += 256) {
    const int nn = it >> 5, o = it & 31;
    float agg = 0.f;
    for (int k = 0; k < FIN; ++k) {
      agg += u0S[nn * FIN + k] * basS[k * 32 + o]
           + u1S[nn * FIN + k] * basS[(FIN + k) * 32 + o];
    }
    float rv = 0.f;
    for (int k = 0; k < FIN; ++k) rv += hT[nn * FIN + k] * rtS[k * 32 + o];
    const int dgi = cntS[nn];
    const float dg = (float)(dgi > 1 ? dgi : 1);
    const float v = agg / dg + rv + biS[o];
    cs[(size_t)(nbase + n0 + nn) * DD + l * 32 + o] = tanhf(v);
  }
}

// ===================== Kernel C: walk + MLP head =====================
__global__ __launch_bounds__(256, 1)
void walk_head(const float* __restrict__ cs, const ushortT* __restrict__ gOut,
               const int* __restrict__ pOut, const int* __restrict__ gSE,
               const float* __restrict__ walk_w, const float* __restrict__ walk_b,
               const float* __restrict__ lin1_w, const float* __restrict__ lin1_b,
               const float* __restrict__ lin2_w, const float* __restrict__ lin2_b,
               float* __restrict__ out) {
  __shared__ float wT[DD * 65];          // [k][j] padded, conflict-free
  __shared__ float wb[64];
  __shared__ float accS[DD];
  __shared__ float part[4 * 64];
  __shared__ int trav[NPER];
  __shared__ float pooledS[DD], hidS[DD], logitsS[8];
  __shared__ int scal[8];
  const int g = blockIdx.x, tid = threadIdx.x;
  const int nbase = g * NPER;

  for (int i = tid; i < DD * 64; i += 256) {
    const int j = i >> 7, k = i & 127;     // coalesced walk_w row reads
    wT[k * 65 + j] = walk_w[j * DD + k];
  }
  if (tid < 64) {
    wb[tid] = (tid < MAXNB) ? walk_b[tid] : 0.f;
    // pad cols 50..63 of wT
    for (int k = 0; k < DD; ++k)
      if (tid >= MAXNB) wT[k * 65 + tid] = 0.f;
  }
  for (int i = tid; i < NPER; i += 256) trav[i] = 0;
  __syncthreads();
  const int startN = gSE[2 * g];
  const int endN = gSE[2 * g + 1];
  if (tid == 0) { scal[0] = startN; scal[1] = 0; scal[6] = 0; trav[startN] = 1; }
  if (tid < DD) accS[tid] = cs[(size_t)(nbase + startN) * DD + tid];
  __syncthreads();

  for (int step = 0; step < MAXW; ++step) {
    {  // partial dots: 4 waves x 32 k's each
      const int w = tid >> 6, j = tid & 63, k0 = w * 32;
      float s = 0.f;
      #pragma unroll
      for (int k = 0; k < 32; ++k) s += wT[(k0 + k) * 65 + j] * accS[k0 + k];
      part[w * 64 + j] = s;
    }
    __syncthreads();
    if (tid < 64) {
      const int j = tid;
      float lg = part[j] + part[64 + j] + part[128 + j] + part[192 + j];
      lg += wb[j];
      const int node = scal[0];
      const int pk = pOut[nbase + node];
      const int off = pk >> 14, c = pk & 16383;
      const int jmax = (c < MAXNB) ? c : MAXNB;
      float myval = -INFINITY;
      if (j < jmax) {
        const int nb = (int)gOut[(size_t)g * EPER + off + j];
        if (!trav[nb]) myval = lg;
      }
      int myidx = j;
      #pragma unroll
      for (int o = 1; o < 64; o <<= 1) {
        const float ov = __shfl_xor(myval, o, 64);
        const int oi = __shfl_xor(myidx, o, 64);
        if (ov > myval || (ov == myval && oi < myidx)) { myval = ov; myidx = oi; }
      }
      if (j == 0) {
        const int done = scal[1];
        const int no_nbr = (c == 0);
        int sel = no_nbr ? (NPER - 1) : (int)gOut[(size_t)g * EPER + off + myidx];
        const int upd = !done;
        const int move = upd && !no_nbr;
        scal[2] = upd;
        scal[3] = no_nbr ? endN : sel;
        if (move) trav[sel] = 1;
        if (upd && (no_nbr || sel == endN)) scal[1] = 1;
        if (move) scal[0] = sel;
      }
    }
    __syncthreads();
    if (scal[2] && tid < DD) accS[tid] += cs[(size_t)(nbase + scal[3]) * DD + tid];
    __syncthreads();
  }

  for (int i = tid; i < NPER; i += 256)
    if (trav[i]) atomicAdd(&scal[6], 1);
  __syncthreads();
  {
    const float tc = (float)scal[6];
    if (tid < DD) pooledS[tid] = accS[tid] / tc;
  }
  __syncthreads();
  if (tid < DD) {
    const float4* w4 = (const float4*)(lin1_w + (size_t)tid * DD);
    float s = lin1_b[tid];
    #pragma unroll 8
    for (int k4 = 0; k4 < DD / 4; ++k4) {
      const float4 wv = w4[k4];
      s += wv.x * pooledS[k4 * 4 + 0] + wv.y * pooledS[k4 * 4 + 1]
         + wv.z * pooledS[k4 * 4 + 2] + wv.w * pooledS[k4 * 4 + 3];
    }
    hidS[tid] = fmaxf(s, 0.f);
  }
  __syncthreads();
  if (tid < NCLS) {
    const float4* w4 = (const float4*)(lin2_w + (size_t)tid * DD);
    float s = lin2_b[tid];
    #pragma unroll 8
    for (int k4 = 0; k4 < DD / 4; ++k4) {
      const float4 wv = w4[k4];
      s += wv.x * hidS[k4 * 4 + 0] + wv.y * hidS[k4 * 4 + 1]
         + wv.z * hidS[k4 * 4 + 2] + wv.w * hidS[k4 * 4 + 3];
    }
    logitsS[tid] = s;
  }
  __syncthreads();
  if (tid < NCLS) {
    float m = logitsS[0];
    for (int c = 1; c < NCLS; ++c) m = fmaxf(m, logitsS[c]);
    float sum = 0.f;
    for (int c = 0; c < NCLS; ++c) sum += expf(logitsS[c] - m);
    const float lse = m + logf(sum);
    out[g * NCLS + tid] = logitsS[tid] - lse;
  }
}

extern "C" void kernel_launch(void* const* d_in, const int* in_sizes, int n_in,
                              void* d_out, int out_size, void* d_ws, size_t ws_size,
                              hipStream_t stream) {
  const float* x = (const float*)d_in[0];
  const int* ei = (const int*)d_in[1];
  const int E = in_sizes[1] / 2;
  const int* esrc = ei;
  const int* edst = ei + E;
  const int* et = (const int*)d_in[2];

  char* ws = (char*)d_ws;
  float* cs = (float*)ws;                                   // 33,554,432 B
  size_t off = (size_t)NGRAPH * NPER * DD * sizeof(float);
  ushortT* gBin = (ushortT*)(ws + off); off += (size_t)NGRAPH * EPER * sizeof(ushortT);  // 2 MB
  ushortT* gOut = (ushortT*)(ws + off); off += (size_t)NGRAPH * EPER * sizeof(ushortT);  // 2 MB
  int* pIn = (int*)(ws + off); off += (size_t)NGRAPH * NPER * sizeof(int);               // 256 KB
  int* pOut = (int*)(ws + off); off += (size_t)NGRAPH * NPER * sizeof(int);              // 256 KB
  int* gSE = (int*)(ws + off); off += (size_t)NGRAPH * 2 * sizeof(int);                  // 1 KB

  build_csr<<<dim3(NGRAPH), dim3(NTA), 0, stream>>>(esrc, edst, et, x, gBin, gOut,
                                                    pIn, pOut, gSE);
  rgcn_layer<NFEAT><<<dim3(NGRAPH * 2), dim3(256), 0, stream>>>(
      x, cs, gBin, pIn, (const float*)d_in[4], (const float*)d_in[5],
      (const float*)d_in[6], (const float*)d_in[7], 0);
  rgcn_layer<32><<<dim3(NGRAPH * 16), dim3(256), 0, stream>>>(
      x, cs, gBin, pIn, (const float*)d_in[8], (const float*)d_in[9],
      (const float*)d_in[10], (const float*)d_in[11], 1);
  rgcn_layer<32><<<dim3(NGRAPH * 16), dim3(256), 0, stream>>>(
      x, cs, gBin, pIn, (const float*)d_in[12], (const float*)d_in[13],
      (const float*)d_in[14], (const float*)d_in[15], 2);
  rgcn_layer<32><<<dim3(NGRAPH * 16), dim3(256), 0, stream>>>(
      x, cs, gBin, pIn, (const float*)d_in[16], (const float*)d_in[17],
      (const float*)d_in[18], (const float*)d_in[19], 3);
  walk_head<<<dim3(NGRAPH), dim3(256), 0, stream>>>(
      cs, gOut, pOut, gSE, (const float*)d_in[20], (const float*)d_in[21],
      (const float*)d_in[22], (const float*)d_in[23], (const float*)d_in[24],
      (const float*)d_in[25], (float*)d_out);
}

// Round 3
// 178.604 us; speedup vs baseline: 3.9254x; 1.5282x over previous
//
#include <hip/hip_runtime.h>
#include <math.h>

#define NGRAPH 128
#define NPER   512
#define EPER   8192
#define NFEAT  4
#define NREL   5
#define DD     128
#define MAXNB  50
#define MAXW   21
#define NCLS   5

typedef unsigned short ushortT;
typedef unsigned char ucharT;

// ===================== Kernel A: build sorted in/out CSRs =====================
// 256 blocks x 1024 thr: blocks [0,128) build in-CSR (sorted by (dst,e)),
// blocks [128,256) build out-CSR (sorted by (src,dst,e)) + start/end nodes.
// Formats (same as prior round): gBin[pos]=(src_local<<3)|rel, gOut[pos]=dst_local,
// pIn/pOut[node]=(offs<<14)|cnt, gSE[g*2+{0,1}]=start/end local index.
#define NTA 1024

__device__ __forceinline__ void scanExcl(const int* cnt, int* offs, int* tA,
                                         int* tB, int tid) {
  if (tid < NPER) tA[tid] = cnt[tid];
  __syncthreads();
  int* a = tA; int* b = tB;
  for (int d = 1; d < NPER; d <<= 1) {
    if (tid < NPER) {
      int v = a[tid];
      if (tid >= d) v += a[tid - d];
      b[tid] = v;
    }
    __syncthreads();
    int* t = a; a = b; b = t;
  }
  if (tid < NPER) offs[tid] = a[tid] - cnt[tid];
  __syncthreads();
}

__global__ __launch_bounds__(NTA, 1)
void build_csr2(const int* __restrict__ esrc, const int* __restrict__ edst,
                const int* __restrict__ etype, const float* __restrict__ x,
                ushortT* __restrict__ gBin, ushortT* __restrict__ gOut,
                int* __restrict__ pIn, int* __restrict__ pOut,
                int* __restrict__ gSE) {
  __shared__ int keyS[EPER];       // bucketed keys (d<<13)|e
  __shared__ int auxS[EPER];       // src-local per edge
  __shared__ ushortT nodS[EPER];   // bucket-node per pos (out-half)
  __shared__ ucharT etyS[EPER];    // edge type (in-half)
  __shared__ int cnt[NPER], offs[NPER], fill[NPER];
  __shared__ int se[2];
  const int bid = blockIdx.x, tid = threadIdx.x;
  const int half = bid >> 7;             // 0: in-CSR, 1: out-CSR
  const int g = bid & 127;
  const int nbase = g * NPER, ebase = g * EPER;

  if (tid < NPER) { cnt[tid] = 0; fill[tid] = 0; }
  if (tid < 2) se[tid] = NPER;
  __syncthreads();

  if (half == 0) {
    // ---- stage + histogram by dst ----
    for (int e = tid; e < EPER; e += NTA) {
      auxS[e] = esrc[ebase + e] - nbase;
      etyS[e] = (ucharT)etype[ebase + e];
      int d = edst[ebase + e] - nbase;
      atomicAdd(&cnt[d], 1);
    }
    __syncthreads();
    scanExcl(cnt, offs, keyS, keyS + NPER, tid);
    // ---- bucket fill (order fixed by rank pass below) ----
    for (int e = tid; e < EPER; e += NTA) {
      int d = edst[ebase + e] - nbase;
      int pos = offs[d] + atomicAdd(&fill[d], 1);
      keyS[pos] = (d << 13) | e;
    }
    __syncthreads();
    // ---- parallel rank within bucket (keys unique) + emit ----
    for (int p = tid; p < EPER; p += NTA) {
      const int k = keyS[p];
      const int n = k >> 13;
      const int o = offs[n], c = cnt[n];
      int r = 0;
      for (int i = 0; i < c; ++i) r += (keyS[o + i] < k);
      const int e = k & (EPER - 1);
      gBin[(size_t)g * EPER + o + r] = (ushortT)((auxS[e] << 3) | (int)etyS[e]);
    }
    if (tid < NPER) pIn[nbase + tid] = (offs[tid] << 14) | cnt[tid];
  } else {
    // ---- stage + histogram by src; detect start/end ----
    for (int e = tid; e < EPER; e += NTA) {
      int s = esrc[ebase + e] - nbase;
      auxS[e] = s;
      atomicAdd(&cnt[s], 1);
    }
    if (tid < NPER) {
      if (x[(size_t)(nbase + tid) * NFEAT + 0] > 0.5f) atomicMin(&se[0], tid);
      if (x[(size_t)(nbase + tid) * NFEAT + 1] > 0.5f) atomicMin(&se[1], tid);
    }
    __syncthreads();
    scanExcl(cnt, offs, keyS, keyS + NPER, tid);
    for (int e = tid; e < EPER; e += NTA) {
      int s = auxS[e];
      int d = edst[ebase + e] - nbase;
      int pos = offs[s] + atomicAdd(&fill[s], 1);
      keyS[pos] = (d << 13) | e;
      nodS[pos] = (ushortT)s;
    }
    __syncthreads();
    for (int p = tid; p < EPER; p += NTA) {
      const int k = keyS[p];
      const int n = (int)nodS[p];
      const int o = offs[n], c = cnt[n];
      int r = 0;
      for (int i = 0; i < c; ++i) r += (keyS[o + i] < k);
      gOut[(size_t)g * EPER + o + r] = (ushortT)(k >> 13);
    }
    if (tid < NPER) pOut[nbase + tid] = (offs[tid] << 14) | cnt[tid];
    if (tid < 2) gSE[g * 2 + tid] = (se[tid] >= NPER) ? 0 : se[tid];
  }
}

// ===================== Kernel B: one RGCN layer as LDS GEMM =====================
// 2 blocks/graph x 512 thr. A = [u0*inv_deg | u1*inv_deg | h] stored k4-major:
// A_s[k4][node 0..255][c]; B = [bas0; bas1; root] o-major: Bt_s[k4][o][c].
// out[n][o] = tanh(sum_k A[n][k]*B[k][o] + bias[o]) -> cs slice l.
template <int FIN>
__global__ __launch_bounds__(512, 1)
void rgcn_layer2(const float* __restrict__ x, float* __restrict__ cs,
                 const ushortT* __restrict__ gBin, const int* __restrict__ pIn,
                 const float* __restrict__ bas, const float* __restrict__ cmp,
                 const float* __restrict__ rt, const float* __restrict__ bi,
                 int l) {
  constexpr int NK4 = (3 * FIN) / 4;     // k4 planes: u0, u1, h
  constexpr int LPN = FIN / 4;           // gather lanes per node
  __shared__ float A_s[NK4 * 256 * 4];
  __shared__ float Bt_s[NK4 * 32 * 4];
  __shared__ float compS[NREL * 2];
  const int bid = blockIdx.x, tid = threadIdx.x;
  const int g = bid >> 1, half = bid & 1;
  const int nbase = g * NPER;
  const int nb2 = nbase + half * 256;    // this block's first graph-node

  // ---- stage B = [bas0; bas1; rt] as Bt[k4][o][c] ----
  for (int idx = tid; idx < NK4 * 128; idx += 512) {
    const int k4 = idx >> 7, rem = idx & 127;
    const int o = rem >> 2, c = rem & 3;
    const int k = k4 * 4 + c;
    float v;
    if (k < FIN) v = bas[k * 32 + o];
    else if (k < 2 * FIN) v = bas[(FIN + (k - FIN)) * 32 + o];
    else v = rt[(k - 2 * FIN) * 32 + o];
    Bt_s[(k4 * 32 + o) * 4 + c] = v;
  }
  if (tid < NREL * 2) compS[tid] = cmp[tid];
  // ---- stage h-part of A (planes 2*LPN .. 3*LPN-1) ----
  for (int idx = tid; idx < 256 * LPN; idx += 512) {
    const int n = idx / LPN, kq = idx % LPN;
    float4 hv;
    if constexpr (FIN == 4)
      hv = *(const float4*)(x + (size_t)(nb2 + n) * NFEAT);
    else
      hv = *(const float4*)(cs + (size_t)(nb2 + n) * DD + (l - 1) * 32 + kq * 4);
    *(float4*)&A_s[((2 * LPN + kq) * 256 + n) * 4] = hv;
  }
  __syncthreads();

  // ---- gather: u_b[n][k-quad q] over sorted in-edges, scaled by 1/deg ----
  for (int t = tid; t < 256 * LPN; t += 512) {
    const int n = t / LPN, q = t % LPN;
    const int pk = pIn[nb2 + n];
    const int off = pk >> 14, c = pk & 16383;
    const float inv = 1.0f / (float)(c > 1 ? c : 1);
    float4 s0 = make_float4(0.f, 0.f, 0.f, 0.f);
    float4 s1 = make_float4(0.f, 0.f, 0.f, 0.f);
    const ushortT* el = gBin + (size_t)g * EPER + off;
    for (int i = 0; i < c; ++i) {
      const int pe = (int)el[i];
      const int s = pe >> 3, r = pe & 7;
      float4 hv;
      if constexpr (FIN == 4)
        hv = *(const float4*)(x + (size_t)(nbase + s) * NFEAT);
      else
        hv = *(const float4*)(cs + (size_t)(nbase + s) * DD + (l - 1) * 32 + q * 4);
      const float c0 = compS[r * 2 + 0], c1 = compS[r * 2 + 1];
      s0.x = fmaf(c0, hv.x, s0.x); s0.y = fmaf(c0, hv.y, s0.y);
      s0.z = fmaf(c0, hv.z, s0.z); s0.w = fmaf(c0, hv.w, s0.w);
      s1.x = fmaf(c1, hv.x, s1.x); s1.y = fmaf(c1, hv.y, s1.y);
      s1.z = fmaf(c1, hv.z, s1.z); s1.w = fmaf(c1, hv.w, s1.w);
    }
    s0.x *= inv; s0.y *= inv; s0.z *= inv; s0.w *= inv;
    s1.x *= inv; s1.y *= inv; s1.z *= inv; s1.w *= inv;
    *(float4*)&A_s[(q * 256 + n) * 4] = s0;
    *(float4*)&A_s[((LPN + q) * 256 + n) * 4] = s1;
  }
  __syncthreads();

  // ---- GEMM: thread tile 2 nodes x 8 outs ----
  // lane mapping keeps 16 node-pairs x 4 o-groups inside each wave
  const int ot = (tid >> 4) & 3;
  const int nt = (tid & 15) | ((tid >> 6) << 4);
  const int n0 = 2 * nt, o0 = 8 * ot;
  float acc[2][8];
#pragma unroll
  for (int i = 0; i < 2; ++i)
#pragma unroll
    for (int j = 0; j < 8; ++j) acc[i][j] = 0.f;
  for (int k4 = 0; k4 < NK4; ++k4) {
    const float4 a0 = *(const float4*)&A_s[(k4 * 256 + n0) * 4];
    const float4 a1 = *(const float4*)&A_s[(k4 * 256 + n0 + 1) * 4];
#pragma unroll
    for (int j = 0; j < 8; ++j) {
      const float4 b = *(const float4*)&Bt_s[(k4 * 32 + o0 + j) * 4];
      acc[0][j] = fmaf(a0.x, b.x, acc[0][j]);
      acc[0][j] = fmaf(a0.y, b.y, acc[0][j]);
      acc[0][j] = fmaf(a0.z, b.z, acc[0][j]);
      acc[0][j] = fmaf(a0.w, b.w, acc[0][j]);
      acc[1][j] = fmaf(a1.x, b.x, acc[1][j]);
      acc[1][j] = fmaf(a1.y, b.y, acc[1][j]);
      acc[1][j] = fmaf(a1.z, b.z, acc[1][j]);
      acc[1][j] = fmaf(a1.w, b.w, acc[1][j]);
    }
  }
#pragma unroll
  for (int i = 0; i < 2; ++i) {
    float4 w0, w1;
    w0.x = tanhf(acc[i][0] + bi[o0 + 0]); w0.y = tanhf(acc[i][1] + bi[o0 + 1]);
    w0.z = tanhf(acc[i][2] + bi[o0 + 2]); w0.w = tanhf(acc[i][3] + bi[o0 + 3]);
    w1.x = tanhf(acc[i][4] + bi[o0 + 4]); w1.y = tanhf(acc[i][5] + bi[o0 + 5]);
    w1.z = tanhf(acc[i][6] + bi[o0 + 6]); w1.w = tanhf(acc[i][7] + bi[o0 + 7]);
    float* dst = cs + (size_t)(nb2 + n0 + i) * DD + l * 32 + o0;
    *(float4*)dst = w0;
    *(float4*)(dst + 4) = w1;
  }
}

// ===================== Kernel C: walk + MLP head (unchanged, proven) =====================
__global__ __launch_bounds__(256, 1)
void walk_head(const float* __restrict__ cs, const ushortT* __restrict__ gOut,
               const int* __restrict__ pOut, const int* __restrict__ gSE,
               const float* __restrict__ walk_w, const float* __restrict__ walk_b,
               const float* __restrict__ lin1_w, const float* __restrict__ lin1_b,
               const float* __restrict__ lin2_w, const float* __restrict__ lin2_b,
               float* __restrict__ out) {
  __shared__ float wT[DD * 65];
  __shared__ float wb[64];
  __shared__ float accS[DD];
  __shared__ float part[4 * 64];
  __shared__ int trav[NPER];
  __shared__ float pooledS[DD], hidS[DD], logitsS[8];
  __shared__ int scal[8];
  const int g = blockIdx.x, tid = threadIdx.x;
  const int nbase = g * NPER;

  for (int i = tid; i < DD * 64; i += 256) {
    const int j = i >> 7, k = i & 127;
    wT[k * 65 + j] = walk_w[j * DD + k];
  }
  if (tid < 64) {
    wb[tid] = (tid < MAXNB) ? walk_b[tid] : 0.f;
    for (int k = 0; k < DD; ++k)
      if (tid >= MAXNB) wT[k * 65 + tid] = 0.f;
  }
  for (int i = tid; i < NPER; i += 256) trav[i] = 0;
  __syncthreads();
  const int startN = gSE[2 * g];
  const int endN = gSE[2 * g + 1];
  if (tid == 0) { scal[0] = startN; scal[1] = 0; scal[6] = 0; trav[startN] = 1; }
  if (tid < DD) accS[tid] = cs[(size_t)(nbase + startN) * DD + tid];
  __syncthreads();

  for (int step = 0; step < MAXW; ++step) {
    {
      const int w = tid >> 6, j = tid & 63, k0 = w * 32;
      float s = 0.f;
#pragma unroll
      for (int k = 0; k < 32; ++k) s += wT[(k0 + k) * 65 + j] * accS[k0 + k];
      part[w * 64 + j] = s;
    }
    __syncthreads();
    if (tid < 64) {
      const int j = tid;
      float lg = part[j] + part[64 + j] + part[128 + j] + part[192 + j];
      lg += wb[j];
      const int node = scal[0];
      const int pk = pOut[nbase + node];
      const int off = pk >> 14, c = pk & 16383;
      const int jmax = (c < MAXNB) ? c : MAXNB;
      float myval = -INFINITY;
      if (j < jmax) {
        const int nb = (int)gOut[(size_t)g * EPER + off + j];
        if (!trav[nb]) myval = lg;
      }
      int myidx = j;
#pragma unroll
      for (int o = 1; o < 64; o <<= 1) {
        const float ov = __shfl_xor(myval, o, 64);
        const int oi = __shfl_xor(myidx, o, 64);
        if (ov > myval || (ov == myval && oi < myidx)) { myval = ov; myidx = oi; }
      }
      if (j == 0) {
        const int done = scal[1];
        const int no_nbr = (c == 0);
        int sel = no_nbr ? (NPER - 1) : (int)gOut[(size_t)g * EPER + off + myidx];
        const int upd = !done;
        const int move = upd && !no_nbr;
        scal[2] = upd;
        scal[3] = no_nbr ? endN : sel;
        if (move) trav[sel] = 1;
        if (upd && (no_nbr || sel == endN)) scal[1] = 1;
        if (move) scal[0] = sel;
      }
    }
    __syncthreads();
    if (scal[2] && tid < DD) accS[tid] += cs[(size_t)(nbase + scal[3]) * DD + tid];
    __syncthreads();
  }

  for (int i = tid; i < NPER; i += 256)
    if (trav[i]) atomicAdd(&scal[6], 1);
  __syncthreads();
  {
    const float tc = (float)scal[6];
    if (tid < DD) pooledS[tid] = accS[tid] / tc;
  }
  __syncthreads();
  if (tid < DD) {
    const float4* w4 = (const float4*)(lin1_w + (size_t)tid * DD);
    float s = lin1_b[tid];
#pragma unroll 8
    for (int k4 = 0; k4 < DD / 4; ++k4) {
      const float4 wv = w4[k4];
      s += wv.x * pooledS[k4 * 4 + 0] + wv.y * pooledS[k4 * 4 + 1]
         + wv.z * pooledS[k4 * 4 + 2] + wv.w * pooledS[k4 * 4 + 3];
    }
    hidS[tid] = fmaxf(s, 0.f);
  }
  __syncthreads();
  if (tid < NCLS) {
    const float4* w4 = (const float4*)(lin2_w + (size_t)tid * DD);
    float s = lin2_b[tid];
#pragma unroll 8
    for (int k4 = 0; k4 < DD / 4; ++k4) {
      const float4 wv = w4[k4];
      s += wv.x * hidS[k4 * 4 + 0] + wv.y * hidS[k4 * 4 + 1]
         + wv.z * hidS[k4 * 4 + 2] + wv.w * hidS[k4 * 4 + 3];
    }
    logitsS[tid] = s;
  }
  __syncthreads();
  if (tid < NCLS) {
    float m = logitsS[0];
    for (int c = 1; c < NCLS; ++c) m = fmaxf(m, logitsS[c]);
    float sum = 0.f;
    for (int c = 0; c < NCLS; ++c) sum += expf(logitsS[c] - m);
    const float lse = m + logf(sum);
    out[g * NCLS + tid] = logitsS[tid] - lse;
  }
}

extern "C" void kernel_launch(void* const* d_in, const int* in_sizes, int n_in,
                              void* d_out, int out_size, void* d_ws, size_t ws_size,
                              hipStream_t stream) {
  const float* x = (const float*)d_in[0];
  const int* ei = (const int*)d_in[1];
  const int E = in_sizes[1] / 2;
  const int* esrc = ei;
  const int* edst = ei + E;
  const int* et = (const int*)d_in[2];

  char* ws = (char*)d_ws;
  float* cs = (float*)ws;
  size_t off = (size_t)NGRAPH * NPER * DD * sizeof(float);                               // 32 MB
  ushortT* gBin = (ushortT*)(ws + off); off += (size_t)NGRAPH * EPER * sizeof(ushortT);  // 2 MB
  ushortT* gOut = (ushortT*)(ws + off); off += (size_t)NGRAPH * EPER * sizeof(ushortT);  // 2 MB
  int* pIn = (int*)(ws + off); off += (size_t)NGRAPH * NPER * sizeof(int);
  int* pOut = (int*)(ws + off); off += (size_t)NGRAPH * NPER * sizeof(int);
  int* gSE = (int*)(ws + off); off += (size_t)NGRAPH * 2 * sizeof(int);

  build_csr2<<<dim3(2 * NGRAPH), dim3(NTA), 0, stream>>>(esrc, edst, et, x, gBin,
                                                         gOut, pIn, pOut, gSE);
  rgcn_layer2<NFEAT><<<dim3(2 * NGRAPH), dim3(512), 0, stream>>>(
      x, cs, gBin, pIn, (const float*)d_in[4], (const float*)d_in[5],
      (const float*)d_in[6], (const float*)d_in[7], 0);
  rgcn_layer2<32><<<dim3(2 * NGRAPH), dim3(512), 0, stream>>>(
      x, cs, gBin, pIn, (const float*)d_in[8], (const float*)d_in[9],
      (const float*)d_in[10], (const float*)d_in[11], 1);
  rgcn_layer2<32><<<dim3(2 * NGRAPH), dim3(512), 0, stream>>>(
      x, cs, gBin, pIn, (const float*)d_in[12], (const float*)d_in[13],
      (const float*)d_in[14], (const float*)d_in[15], 2);
  rgcn_layer2<32><<<dim3(2 * NGRAPH), dim3(512), 0, stream>>>(
      x, cs, gBin, pIn, (const float*)d_in[16], (const float*)d_in[17],
      (const float*)d_in[18], (const float*)d_in[19], 3);
  walk_head<<<dim3(NGRAPH), dim3(256), 0, stream>>>(
      cs, gOut, pOut, gSE, (const float*)d_in[20], (const float*)d_in[21],
      (const float*)d_in[22], (const float*)d_in[23], (const float*)d_in[24],
      (const float*)d_in[25], (float*)d_out);
}